// Round 1
// baseline (262.634 us; speedup 1.0000x reference)
//
#include <hip/hip_runtime.h>

// Problem: B=256, N=131072, F=16. Two-pass causal FIR with masking:
//   v[i] = (i>=16) ? x[i] + sum_{j<16} h[j]*x[i-1-j] : 0
//   y[i] = (i>=16) ? v[i] + sum_{j<16} h[15-j]*v[i-1-j] : 0
// For i >= 32 all v terms are unmasked, so y = 33-tap conv with
// g = conv([1,h], [1,reverse(h)])  (g[m] = sum_{a+b=m} k[a]*kr[b]).
// i in [16,32) handled explicitly; i < 16 is zero.

#define NROW 131072

__global__ void compute_g_kernel(const float* __restrict__ h, float* __restrict__ g) {
    int m = threadIdx.x;
    if (m < 33) {
        float s = 0.f;
        for (int a = 0; a <= 16; ++a) {
            int b = m - a;
            if (b < 0 || b > 16) continue;
            float ka = (a == 0) ? 1.f : h[a - 1];
            float kb = (b == 0) ? 1.f : h[16 - b];
            s += ka * kb;
        }
        g[m] = s;
    }
}

// One thread = 16 consecutive outputs from a 48-float register window.
// Block = 256 threads = 4096 outputs; 32 blocks/row x 256 rows = 8192 blocks.
__global__ __launch_bounds__(256) void fir2_kernel(const float* __restrict__ x,
                                                   const float* __restrict__ h,
                                                   const float* __restrict__ g,
                                                   float* __restrict__ y) {
    const int bid = blockIdx.x;
    const int row = bid >> 5;   // 32 chunks per row
    const int chunk = bid & 31;
    const int i0 = chunk * 4096 + (int)threadIdx.x * 16;
    const float* __restrict__ xr = x + (size_t)row * NROW;
    float* __restrict__ yr = y + (size_t)row * NROW;

    // Window w[k] = x[i0 - 32 + k], k = 0..47 (OOB -> 0, only i0<32 hits it).
    float w[48];
#pragma unroll
    for (int k = 0; k < 12; ++k) {
        const int idx = i0 - 32 + 4 * k;
        float4 val;
        if (idx >= 0) val = *(const float4*)(xr + idx);
        else          val = make_float4(0.f, 0.f, 0.f, 0.f);
        w[4 * k + 0] = val.x; w[4 * k + 1] = val.y;
        w[4 * k + 2] = val.z; w[4 * k + 3] = val.w;
    }

    float o[16];
    if (i0 >= 32) {
        // Generic path: y[i0+c] = sum_{m=0..32} g[m] * w[c + 32 - m]
        float gg[33];
#pragma unroll
        for (int m = 0; m < 33; ++m) gg[m] = g[m];   // uniform -> scalar loads
#pragma unroll
        for (int c = 0; c < 16; ++c) {
            float s = 0.f;
#pragma unroll
            for (int m = 0; m < 33; ++m) s += gg[m] * w[c + 32 - m];
            o[c] = s;
        }
    } else if (i0 == 0) {
#pragma unroll
        for (int c = 0; c < 16; ++c) o[c] = 0.f;     // y[0..15] = 0
    } else {
        // i0 == 16: explicit two-stage with v masked below 16.
        // Here w[k] = x[k - 16], i.e. x[p] = w[p + 16] for p in [0, 31].
        float hh[16];
#pragma unroll
        for (int j = 0; j < 16; ++j) hh[j] = h[j];
        float v[16];                                  // v[u] = v_global[16+u]
#pragma unroll
        for (int u = 0; u < 16; ++u) {
            const int p = 16 + u;
            float s = w[p + 16];                      // x[p]
#pragma unroll
            for (int j = 0; j < 16; ++j) s += hh[j] * w[p + 15 - j]; // x[p-1-j]
            v[u] = s;
        }
#pragma unroll
        for (int u = 0; u < 16; ++u) {
            float s = v[u];
#pragma unroll
            for (int j = 0; j < 16; ++j) {
                if (j <= u - 1) s += hh[15 - j] * v[u - 1 - j]; // only v>=16 terms
            }
            o[u] = s;
        }
    }

#pragma unroll
    for (int k = 0; k < 4; ++k) {
        float4 val = make_float4(o[4 * k + 0], o[4 * k + 1],
                                 o[4 * k + 2], o[4 * k + 3]);
        *(float4*)(yr + i0 + 4 * k) = val;
    }
}

extern "C" void kernel_launch(void* const* d_in, const int* in_sizes, int n_in,
                              void* d_out, int out_size, void* d_ws, size_t ws_size,
                              hipStream_t stream) {
    const float* x = (const float*)d_in[0];   // (256, 131072) fp32
    const float* h = (const float*)d_in[1];   // (1, 16) fp32
    float* y = (float*)d_out;                 // (256, 131072) fp32
    float* g = (float*)d_ws;                  // 33 floats of scratch

    compute_g_kernel<<<1, 64, 0, stream>>>(h, g);
    fir2_kernel<<<8192, 256, 0, stream>>>(x, h, g, y);
}

// Round 2
// 247.557 us; speedup vs baseline: 1.0609x; 1.0609x over previous
//
#include <hip/hip_runtime.h>

// Problem: B=256, N=131072, F=16. Two-pass causal FIR with masking:
//   v[i] = (i>=16) ? x[i] + sum_{j<16} h[j]*x[i-1-j] : 0
//   y[i] = (i>=16) ? v[i] + sum_{j<16} h[15-j]*v[i-1-j] : 0
// For i >= 32 all v terms are unmasked, so y = 33-tap conv with
// g = conv([1,h], [1,reverse(h)]). i in [16,32) explicit; i < 16 zero.
//
// R1 -> R2: kernel was latency-bound (23% HBM, 19% VALU, 47% occ) because
// per-thread consecutive-16 ownership made every global ld/st 64B-strided
// per lane. Now: LDS-stage the 4096+32 tile with lane-contiguous float4
// loads (coalesced, 5 independent loads before one barrier), compute from
// LDS with +1-per-16 padding (stride 17 = conflict-free b32 reads).

#define NROW 131072
#define TILE 4096
#define HALO 32
// padded index: insert one pad float after every 16
#define PAD(i) ((i) + ((i) >> 4))
#define LDS_FLOATS (PAD(TILE + HALO - 1) + 1)

__global__ void compute_g_kernel(const float* __restrict__ h, float* __restrict__ g) {
    int m = threadIdx.x;
    if (m < 33) {
        float s = 0.f;
        for (int a = 0; a <= 16; ++a) {
            int b = m - a;
            if (b < 0 || b > 16) continue;
            float ka = (a == 0) ? 1.f : h[a - 1];
            float kb = (b == 0) ? 1.f : h[16 - b];
            s += ka * kb;
        }
        g[m] = s;
    }
}

__global__ __launch_bounds__(256) void fir2_kernel(const float* __restrict__ x,
                                                   const float* __restrict__ h,
                                                   const float* __restrict__ g,
                                                   float* __restrict__ y) {
    __shared__ float lds[LDS_FLOATS];

    const int bid = blockIdx.x;
    const int row = bid >> 5;   // 32 chunks per row
    const int chunk = bid & 31;
    const int i0 = chunk * TILE;            // tile base (outputs [i0, i0+4096))
    const int t = (int)threadIdx.x;
    const float* __restrict__ xr = x + (size_t)row * NROW;
    float* __restrict__ yr = y + (size_t)row * NROW;

    // ---- Stage tile [i0-32, i0+4096) into padded LDS, coalesced float4 ----
    const int base = i0 - HALO;
#pragma unroll
    for (int k = 0; k < 4; ++k) {
        const int f = t + 256 * k;          // float4 index within tile
        const int gidx = base + 4 * f;      // global float index
        float4 v;
        if (gidx >= 0) v = *(const float4*)(xr + gidx);
        else           v = make_float4(0.f, 0.f, 0.f, 0.f);
        const int l = PAD(4 * f);           // 4*f%16 <= 12 -> no pad crossing
        lds[l + 0] = v.x; lds[l + 1] = v.y; lds[l + 2] = v.z; lds[l + 3] = v.w;
    }
    if (t < 8) {                            // halo tail: float4 1024..1031
        const int f = 1024 + t;
        const int gidx = base + 4 * f;
        float4 v = *(const float4*)(xr + gidx);  // gidx = i0+4064+4t, always >= 0
        const int l = PAD(4 * f);
        lds[l + 0] = v.x; lds[l + 1] = v.y; lds[l + 2] = v.z; lds[l + 3] = v.w;
    }
    __syncthreads();

    // ---- Each thread: 16 outputs at i0t = i0 + 16*t, window from LDS ----
    const int i0t = i0 + 16 * t;
    // window w[k] = x[i0t - 32 + k] = lds[pad(16*t + k)], k = 0..47
    float w[48];
#pragma unroll
    for (int k = 0; k < 48; ++k) w[k] = lds[17 * t + k + (k >> 4)];

    float o[16];
    if (i0t >= 32) {
        float gg[33];
#pragma unroll
        for (int m = 0; m < 33; ++m) gg[m] = g[m];   // uniform -> s_load
#pragma unroll
        for (int c = 0; c < 16; ++c) {
            float s = 0.f;
#pragma unroll
            for (int m = 0; m < 33; ++m) s += gg[m] * w[c + 32 - m];
            o[c] = s;
        }
    } else if (i0t == 0) {
#pragma unroll
        for (int c = 0; c < 16; ++c) o[c] = 0.f;
    } else {
        // i0t == 16: two-stage with v masked below 16; w[k] = x[k-16] here.
        float hh[16];
#pragma unroll
        for (int j = 0; j < 16; ++j) hh[j] = h[j];
        float v[16];                                  // v[u] = v_global[16+u]
#pragma unroll
        for (int u = 0; u < 16; ++u) {
            const int p = 16 + u;
            float s = w[p + 16];                      // x[p]
#pragma unroll
            for (int j = 0; j < 16; ++j) s += hh[j] * w[p + 15 - j];
            v[u] = s;
        }
#pragma unroll
        for (int u = 0; u < 16; ++u) {
            float s = v[u];
#pragma unroll
            for (int j = 0; j < 16; ++j) {
                if (j <= u - 1) s += hh[15 - j] * v[u - 1 - j];
            }
            o[u] = s;
        }
    }

#pragma unroll
    for (int k = 0; k < 4; ++k) {
        float4 val = make_float4(o[4 * k + 0], o[4 * k + 1],
                                 o[4 * k + 2], o[4 * k + 3]);
        *(float4*)(yr + i0t + 4 * k) = val;
    }
}

extern "C" void kernel_launch(void* const* d_in, const int* in_sizes, int n_in,
                              void* d_out, int out_size, void* d_ws, size_t ws_size,
                              hipStream_t stream) {
    const float* x = (const float*)d_in[0];   // (256, 131072) fp32
    const float* h = (const float*)d_in[1];   // (1, 16) fp32
    float* y = (float*)d_out;                 // (256, 131072) fp32
    float* g = (float*)d_ws;                  // 33 floats of scratch

    compute_g_kernel<<<1, 64, 0, stream>>>(h, g);
    fir2_kernel<<<8192, 256, 0, stream>>>(x, h, g, y);
}